// Round 4
// baseline (2050.268 us; speedup 1.0000x reference)
//
#include <hip/hip_runtime.h>
#include <hip/hip_bf16.h>
#include <math.h>

typedef __hip_bfloat16 bf16;
typedef __attribute__((ext_vector_type(8))) __bf16 bf16x8;
typedef __attribute__((ext_vector_type(4))) float f32x4;
typedef __attribute__((ext_vector_type(4))) unsigned u32x4;

#define NB 64
#define NTOK 256
#define CDIM 1024
#define NH 16
#define DH 64
#define DFF 4096
#define MROWS (NB * NTOK)  // 16384

__device__ __forceinline__ float lo16(unsigned u) { return __uint_as_float(u << 16); }
__device__ __forceinline__ float hi16(unsigned u) { return __uint_as_float(u & 0xffff0000u); }

__device__ __forceinline__ float gelu_f(float x) {
    float x3 = x * x * x;
    return 0.5f * x * (1.0f + tanhf(0.7978845608028654f * (x + 0.044715f * x3)));
}

// ------------- transpose + downcast: in fp32 [R][C] -> out bf16 [C][R] -------------
__global__ void transpose_f32_bf16(const float* __restrict__ in, bf16* __restrict__ out,
                                   int R, int Cc) {
    __shared__ bf16 tile[32][33];
    int c0 = blockIdx.x * 32, r0 = blockIdx.y * 32;
    int t = threadIdx.x;
    int r = t >> 5, c = t & 31;
#pragma unroll
    for (int i = 0; i < 4; i++)
        tile[r + i * 8][c] = (bf16)in[(size_t)(r0 + r + i * 8) * Cc + c0 + c];
    __syncthreads();
#pragma unroll
    for (int i = 0; i < 4; i++)
        out[(size_t)(c0 + r + i * 8) * R + r0 + c] = tile[c][r + i * 8];
}

// ------------- layernorm: fp32 in -> bf16 out; one row (C=1024) per block -------------
__global__ __launch_bounds__(256) void ln_kernel(const float* __restrict__ xin,
                                                 const float* __restrict__ g,
                                                 const float* __restrict__ b,
                                                 bf16* __restrict__ outp) {
    __shared__ float red[8];
    int row = blockIdx.x, t = threadIdx.x;
    float4 v = ((const float4*)(xin + (size_t)row * CDIM))[t];
    float s = v.x + v.y + v.z + v.w;
    float q = v.x * v.x + v.y * v.y + v.z * v.z + v.w * v.w;
#pragma unroll
    for (int off = 32; off > 0; off >>= 1) {
        s += __shfl_down(s, off);
        q += __shfl_down(q, off);
    }
    int wave = t >> 6;
    if ((t & 63) == 0) { red[wave] = s; red[4 + wave] = q; }
    __syncthreads();
    float st = red[0] + red[1] + red[2] + red[3];
    float qt = red[4] + red[5] + red[6] + red[7];
    float mu = st * (1.0f / CDIM);
    float rstd = rsqrtf(qt * (1.0f / CDIM) - mu * mu + 1e-5f);
    float4 gv = ((const float4*)g)[t];
    float4 bv = ((const float4*)b)[t];
    bf16* orow = outp + (size_t)row * CDIM + t * 4;
    orow[0] = (bf16)((v.x - mu) * rstd * gv.x + bv.x);
    orow[1] = (bf16)((v.y - mu) * rstd * gv.y + bv.y);
    orow[2] = (bf16)((v.z - mu) * rstd * gv.z + bv.z);
    orow[3] = (bf16)((v.w - mu) * rstd * gv.w + bv.w);
}

// ------------- bias gather: biasT[h][m][n] = rpb[idx[n*256+m]*16+h] (fp32) -------------
// (n = query, m = key; storage coalesced over n)
__global__ void biasT_kernel(const int* __restrict__ idx, const float* __restrict__ rpb,
                             float* __restrict__ bT) {
    int e = blockIdx.x * 256 + threadIdx.x;
    int n = e & 255, m = (e >> 8) & 255, h = e >> 16;
    bT[e] = rpb[idx[n * 256 + m] * NH + h];
}

// ------------- GEMM: C[M,N] = A[M,K] @ Bt[N,K]^T  (A,Bt bf16; fp32 acc) -------------
// LDS chunk ch = kk*128 + r holds A[row0+r][k0 + kk*8 .. +8] (16B)
// mode 0: +bias, q*=0.125 -> scatter to bf16 qkv buffer [3][Bc][H][N][DH] (stride qstride)
// mode 2: +bias, gelu -> bf16 row-major
// mode 3: +bias, +fp32 resid -> fp32 row-major (outp may alias resid; same-thread RMW)
__global__ __launch_bounds__(256) void gemm_bt_kernel(
    const bf16* __restrict__ Abf, const bf16* __restrict__ Btbf,
    const float* __restrict__ bias, const float* resid,
    void* outp, size_t qstride, int M, int N, int K, int mode) {
    __shared__ __align__(16) u32x4 As[1024];
    __shared__ __align__(16) u32x4 Bs[1024];
    const unsigned short* A = (const unsigned short*)Abf;
    const unsigned short* Bt = (const unsigned short*)Btbf;
    int tid = threadIdx.x;
    int wave = tid >> 6, lane = tid & 63;
    int quad = lane >> 4, lr = lane & 15;
    int wm = (wave >> 1) << 6, wn = (wave & 1) << 6;
    size_t row0 = (size_t)blockIdx.y << 7;
    size_t col0 = (size_t)blockIdx.x << 7;
    const unsigned short* Ag = A + row0 * K;
    const unsigned short* Bg = Bt + col0 * K;
    f32x4 acc[4][4] = {};

    for (int k0 = 0; k0 < K; k0 += 64) {
        u32x4 ra[4], rb[4];
#pragma unroll
        for (int ii = 0; ii < 4; ii++) {
            int ch = ii * 256 + tid;
            int kk = ch >> 7;
            int r = ch & 127;
            ra[ii] = *(const u32x4*)(Ag + (size_t)r * K + (k0 + kk * 8));
            rb[ii] = *(const u32x4*)(Bg + (size_t)r * K + (k0 + kk * 8));
        }
        __syncthreads();
#pragma unroll
        for (int ii = 0; ii < 4; ii++) {
            As[ii * 256 + tid] = ra[ii];
            Bs[ii * 256 + tid] = rb[ii];
        }
        __syncthreads();
#pragma unroll
        for (int ks = 0; ks < 2; ks++) {
            bf16x8 af[4], bfr[4];
#pragma unroll
            for (int i = 0; i < 4; i++) {
                af[i]  = __builtin_bit_cast(bf16x8, As[(ks * 4 + quad) * 128 + wm + i * 16 + lr]);
                bfr[i] = __builtin_bit_cast(bf16x8, Bs[(ks * 4 + quad) * 128 + wn + i * 16 + lr]);
            }
#pragma unroll
            for (int i = 0; i < 4; i++)
#pragma unroll
                for (int j = 0; j < 4; j++)
                    acc[i][j] = __builtin_amdgcn_mfma_f32_16x16x32_bf16(af[i], bfr[j],
                                                                        acc[i][j], 0, 0, 0);
        }
    }

    float bc[4];
#pragma unroll
    for (int j = 0; j < 4; j++) bc[j] = bias[col0 + wn + j * 16 + lr];
#pragma unroll
    for (int i = 0; i < 4; i++) {
#pragma unroll
        for (int r = 0; r < 4; r++) {
            int R = (int)row0 + wm + i * 16 + quad * 4 + r;
#pragma unroll
            for (int j = 0; j < 4; j++) {
                int Cc = (int)col0 + wn + j * 16 + lr;
                float val = acc[i][j][r] + bc[j];
                if (mode == 0) {
                    int t3 = Cc >> 10, rem = Cc & 1023;
                    int head = rem >> 6, d = rem & 63;
                    int lb = R >> 8, nn = R & 255;  // batch-local within chunk
                    if (t3 == 0) val *= 0.125f;     // Dh^-0.5
                    ((bf16*)outp)[(size_t)t3 * qstride +
                                  ((size_t)((lb << 4) + head) * NTOK + nn) * DH + d] = (bf16)val;
                } else if (mode == 2) {
                    ((bf16*)outp)[(size_t)R * N + Cc] = (bf16)gelu_f(val);
                } else {
                    val += resid[(size_t)R * N + Cc];
                    ((float*)outp)[(size_t)R * N + Cc] = val;
                }
            }
        }
    }
}

// ------------- attention: one block per (local b, h), thread n = query row -------------
__device__ __forceinline__ float dot64(const float* qv, const unsigned* kr) {
    float s0 = 0, s1 = 0, s2 = 0, s3 = 0;
#pragma unroll
    for (int i = 0; i < 32; i += 4) {
        unsigned a = kr[i], b = kr[i + 1], c = kr[i + 2], d = kr[i + 3];
        s0 += qv[2 * i + 0] * lo16(a) + qv[2 * i + 1] * hi16(a);
        s1 += qv[2 * i + 2] * lo16(b) + qv[2 * i + 3] * hi16(b);
        s2 += qv[2 * i + 4] * lo16(c) + qv[2 * i + 5] * hi16(c);
        s3 += qv[2 * i + 6] * lo16(d) + qv[2 * i + 7] * hi16(d);
    }
    return (s0 + s1) + (s2 + s3);
}

__global__ __launch_bounds__(256) void attn_kernel(const bf16* __restrict__ qkv,
                                                   const float* __restrict__ biasT,
                                                   bf16* __restrict__ outp, size_t qstride) {
    __shared__ unsigned Ks[NTOK * DH / 2];  // 32 KB
    __shared__ unsigned Vs[NTOK * DH / 2];  // 32 KB
    int bh = blockIdx.x;  // (batch-local)*16 + head
    int lb = bh >> 4, h = bh & 15;
    int n = threadIdx.x;
    const unsigned* kg = (const unsigned*)(qkv + qstride + (size_t)bh * NTOK * DH);
    const unsigned* vg = (const unsigned*)(qkv + 2 * qstride + (size_t)bh * NTOK * DH);
    for (int i = n; i < NTOK * DH / 2; i += 256) { Ks[i] = kg[i]; Vs[i] = vg[i]; }
    const unsigned* qg = (const unsigned*)(qkv + (size_t)bh * NTOK * DH + (size_t)n * DH);
    float qv[64];
#pragma unroll
    for (int i = 0; i < 32; i++) { unsigned u = qg[i]; qv[2 * i] = lo16(u); qv[2 * i + 1] = hi16(u); }
    __syncthreads();
    const float* bT = biasT + (size_t)h * NTOK * NTOK + n;  // [m][n], coalesced over n
    float mx = -1e30f;
    for (int m = 0; m < NTOK; m++) {
        float s = dot64(qv, Ks + m * 32) + bT[(size_t)m * NTOK];
        mx = fmaxf(mx, s);
    }
    float o[64];
#pragma unroll
    for (int i = 0; i < 64; i++) o[i] = 0.f;
    float L = 0.f;
    for (int m = 0; m < NTOK; m++) {
        float s = dot64(qv, Ks + m * 32) + bT[(size_t)m * NTOK];
        float p = __expf(s - mx);
        L += p;
        const unsigned* vr = Vs + m * 32;
#pragma unroll
        for (int i = 0; i < 32; i++) {
            unsigned u = vr[i];
            o[2 * i] += p * lo16(u);
            o[2 * i + 1] += p * hi16(u);
        }
    }
    float inv = 1.0f / L;
    bf16* orow = outp + ((size_t)(lb * NTOK + n)) * CDIM + h * DH;
#pragma unroll
    for (int d = 0; d < 64; d++) orow[d] = (bf16)(o[d] * inv);
}

// ---------------- launch ----------------
extern "C" void kernel_launch(void* const* d_in, const int* in_sizes, int n_in,
                              void* d_out, int out_size, void* d_ws, size_t ws_size,
                              hipStream_t stream) {
    const float* x      = (const float*)d_in[0];
    const int*   rpi    = (const int*)d_in[1];
    const float* qkv_w  = (const float*)d_in[2];
    const float* qkv_b  = (const float*)d_in[3];
    const float* proj_w = (const float*)d_in[4];
    const float* proj_b = (const float*)d_in[5];
    const float* rpb    = (const float*)d_in[6];
    const float* ln1g   = (const float*)d_in[7];
    const float* ln1b   = (const float*)d_in[8];
    const float* ln2g   = (const float*)d_in[9];
    const float* ln2b   = (const float*)d_in[10];
    const float* fc1_w  = (const float*)d_in[11];
    const float* fc1_b  = (const float*)d_in[12];
    const float* fc2_w  = (const float*)d_in[13];
    const float* fc2_b  = (const float*)d_in[14];
    float* out = (float*)d_out;
    char* ws = (char*)d_ws;

    // --- fixed region: bf16 transposed weights + fp32 biasT (29,360,128 B) ---
    bf16* qkvT   = (bf16*)(ws);                 // 6,291,456
    bf16* projT  = (bf16*)(ws + 6291456ull);    // 2,097,152
    bf16* fc1T   = (bf16*)(ws + 8388608ull);    // 8,388,608
    bf16* fc2T   = (bf16*)(ws + 16777216ull);   // 8,388,608
    float* biasT = (float*)(ws + 25165824ull);  // 4,194,304
    const size_t fixed_end = 29360128ull;

    // --- adaptive chunk: per-row bytes = 2048 (hbuf) + 8192 (qkv or ff) ---
    long long avail = (long long)ws_size - (long long)fixed_end;
    long long rc = avail / 10240;
    rc &= ~255LL;                       // whole 256-row batches (keeps attn windows intact)
    if (rc < 256) rc = 256;
    if (rc > MROWS) rc = MROWS;
    const int Rc = (int)rc;
    bf16* hbuf   = (bf16*)(ws + fixed_end);                        // Rc*1024 bf16
    bf16* bigbuf = (bf16*)(ws + fixed_end + (size_t)Rc * 2048ull); // Rc*3072 or Rc*4096 bf16

    transpose_f32_bf16<<<dim3(3072 / 32, 1024 / 32), 256, 0, stream>>>(qkv_w, qkvT, 1024, 3072);
    transpose_f32_bf16<<<dim3(1024 / 32, 1024 / 32), 256, 0, stream>>>(proj_w, projT, 1024, 1024);
    transpose_f32_bf16<<<dim3(4096 / 32, 1024 / 32), 256, 0, stream>>>(fc1_w, fc1T, 1024, 4096);
    transpose_f32_bf16<<<dim3(1024 / 32, 4096 / 32), 256, 0, stream>>>(fc2_w, fc2T, 4096, 1024);
    biasT_kernel<<<4096, 256, 0, stream>>>(rpi, rpb, biasT);

    // --- phase A: LN1 -> qkv -> attention -> proj + residual ---
    for (int r0 = 0; r0 < MROWS; r0 += Rc) {
        int m = MROWS - r0 < Rc ? MROWS - r0 : Rc;
        size_t qs = (size_t)m * 1024;  // per-q/k/v stride in bf16 elems
        ln_kernel<<<m, 256, 0, stream>>>(x + (size_t)r0 * CDIM, ln1g, ln1b, hbuf);
        gemm_bt_kernel<<<dim3(3072 / 128, m / 128), 256, 0, stream>>>(
            hbuf, qkvT, qkv_b, nullptr, bigbuf, qs, m, 3072, 1024, 0);
        attn_kernel<<<(m / 256) * NH, 256, 0, stream>>>(bigbuf, biasT, hbuf, qs);
        gemm_bt_kernel<<<dim3(1024 / 128, m / 128), 256, 0, stream>>>(
            hbuf, projT, proj_b, x + (size_t)r0 * CDIM, out + (size_t)r0 * CDIM, 0,
            m, 1024, 1024, 3);
    }

    // --- phase B: LN2 -> fc1+gelu -> fc2 + residual ---
    for (int r0 = 0; r0 < MROWS; r0 += Rc) {
        int m = MROWS - r0 < Rc ? MROWS - r0 : Rc;
        ln_kernel<<<m, 256, 0, stream>>>(out + (size_t)r0 * CDIM, ln2g, ln2b, hbuf);
        gemm_bt_kernel<<<dim3(4096 / 128, m / 128), 256, 0, stream>>>(
            hbuf, fc1T, fc1_b, nullptr, bigbuf, 0, m, 4096, 1024, 2);
        gemm_bt_kernel<<<dim3(1024 / 128, m / 128), 256, 0, stream>>>(
            bigbuf, fc2T, fc2_b, out + (size_t)r0 * CDIM, out + (size_t)r0 * CDIM, 0,
            m, 1024, 4096, 3);
    }
}

// Round 5
// 1498.930 us; speedup vs baseline: 1.3678x; 1.3678x over previous
//
#include <hip/hip_runtime.h>
#include <hip/hip_bf16.h>
#include <math.h>

typedef __hip_bfloat16 bf16;
typedef __attribute__((ext_vector_type(8))) __bf16 bf16x8;
typedef __attribute__((ext_vector_type(4))) float f32x4;
typedef __attribute__((ext_vector_type(4))) unsigned u32x4;

#define NB 64
#define NTOK 256
#define CDIM 1024
#define NH 16
#define DH 64
#define DFF 4096
#define MROWS (NB * NTOK)  // 16384

__device__ __forceinline__ float gelu_f(float x) {
    float x3 = x * x * x;
    return 0.5f * x * (1.0f + tanhf(0.7978845608028654f * (x + 0.044715f * x3)));
}

// ------------- transpose + downcast: in fp32 [R][C] -> out bf16 [C][R] -------------
__global__ void transpose_f32_bf16(const float* __restrict__ in, bf16* __restrict__ out,
                                   int R, int Cc) {
    __shared__ bf16 tile[32][33];
    int c0 = blockIdx.x * 32, r0 = blockIdx.y * 32;
    int t = threadIdx.x;
    int r = t >> 5, c = t & 31;
#pragma unroll
    for (int i = 0; i < 4; i++)
        tile[r + i * 8][c] = (bf16)in[(size_t)(r0 + r + i * 8) * Cc + c0 + c];
    __syncthreads();
#pragma unroll
    for (int i = 0; i < 4; i++)
        out[(size_t)(c0 + r + i * 8) * R + r0 + c] = tile[c][r + i * 8];
}

// ------------- layernorm: fp32 in -> bf16 out; one row (C=1024) per block -------------
__global__ __launch_bounds__(256) void ln_kernel(const float* __restrict__ xin,
                                                 const float* __restrict__ g,
                                                 const float* __restrict__ b,
                                                 bf16* __restrict__ outp) {
    __shared__ float red[8];
    int row = blockIdx.x, t = threadIdx.x;
    float4 v = ((const float4*)(xin + (size_t)row * CDIM))[t];
    float s = v.x + v.y + v.z + v.w;
    float q = v.x * v.x + v.y * v.y + v.z * v.z + v.w * v.w;
#pragma unroll
    for (int off = 32; off > 0; off >>= 1) {
        s += __shfl_down(s, off);
        q += __shfl_down(q, off);
    }
    int wave = t >> 6;
    if ((t & 63) == 0) { red[wave] = s; red[4 + wave] = q; }
    __syncthreads();
    float st = red[0] + red[1] + red[2] + red[3];
    float qt = red[4] + red[5] + red[6] + red[7];
    float mu = st * (1.0f / CDIM);
    float rstd = rsqrtf(qt * (1.0f / CDIM) - mu * mu + 1e-5f);
    float4 gv = ((const float4*)g)[t];
    float4 bv = ((const float4*)b)[t];
    bf16* orow = outp + (size_t)row * CDIM + t * 4;
    orow[0] = (bf16)((v.x - mu) * rstd * gv.x + bv.x);
    orow[1] = (bf16)((v.y - mu) * rstd * gv.y + bv.y);
    orow[2] = (bf16)((v.z - mu) * rstd * gv.z + bv.z);
    orow[3] = (bf16)((v.w - mu) * rstd * gv.w + bv.w);
}

// ------------- bias gather: biasq[h][q][k] = rpb[idx[q*256+k]*16+h] (fp32) -------------
// coalesced over k (the lane dimension in the attention S-epilogue)
__global__ void biasq_kernel(const int* __restrict__ idx, const float* __restrict__ rpb,
                             float* __restrict__ bq) {
    int e = blockIdx.x * 256 + threadIdx.x;
    int k = e & 255, q = (e >> 8) & 255, h = e >> 16;
    bq[e] = rpb[idx[q * 256 + k] * NH + h];
}

// ------------- GEMM: C[M,N] = A[M,K] @ Bt[N,K]^T  (A,Bt bf16; fp32 acc) -------------
// mode 0: +bias, q*=0.125 -> scatter to bf16 qkv buffer [3][Bc][H][N][DH] (stride qstride)
// mode 2: +bias, gelu -> bf16 row-major
// mode 3: +bias, +fp32 resid -> fp32 row-major (outp may alias resid; same-thread RMW)
__global__ __launch_bounds__(256) void gemm_bt_kernel(
    const bf16* __restrict__ Abf, const bf16* __restrict__ Btbf,
    const float* __restrict__ bias, const float* resid,
    void* outp, size_t qstride, int M, int N, int K, int mode) {
    __shared__ __align__(16) u32x4 As[1024];
    __shared__ __align__(16) u32x4 Bs[1024];
    const unsigned short* A = (const unsigned short*)Abf;
    const unsigned short* Bt = (const unsigned short*)Btbf;
    int tid = threadIdx.x;
    int wave = tid >> 6, lane = tid & 63;
    int quad = lane >> 4, lr = lane & 15;
    int wm = (wave >> 1) << 6, wn = (wave & 1) << 6;
    size_t row0 = (size_t)blockIdx.y << 7;
    size_t col0 = (size_t)blockIdx.x << 7;
    const unsigned short* Ag = A + row0 * K;
    const unsigned short* Bg = Bt + col0 * K;
    f32x4 acc[4][4] = {};

    for (int k0 = 0; k0 < K; k0 += 64) {
        u32x4 ra[4], rb[4];
#pragma unroll
        for (int ii = 0; ii < 4; ii++) {
            int ch = ii * 256 + tid;
            int kk = ch >> 7;
            int r = ch & 127;
            ra[ii] = *(const u32x4*)(Ag + (size_t)r * K + (k0 + kk * 8));
            rb[ii] = *(const u32x4*)(Bg + (size_t)r * K + (k0 + kk * 8));
        }
        __syncthreads();
#pragma unroll
        for (int ii = 0; ii < 4; ii++) {
            As[ii * 256 + tid] = ra[ii];
            Bs[ii * 256 + tid] = rb[ii];
        }
        __syncthreads();
#pragma unroll
        for (int ks = 0; ks < 2; ks++) {
            bf16x8 af[4], bfr[4];
#pragma unroll
            for (int i = 0; i < 4; i++) {
                af[i]  = __builtin_bit_cast(bf16x8, As[(ks * 4 + quad) * 128 + wm + i * 16 + lr]);
                bfr[i] = __builtin_bit_cast(bf16x8, Bs[(ks * 4 + quad) * 128 + wn + i * 16 + lr]);
            }
#pragma unroll
            for (int i = 0; i < 4; i++)
#pragma unroll
                for (int j = 0; j < 4; j++)
                    acc[i][j] = __builtin_amdgcn_mfma_f32_16x16x32_bf16(af[i], bfr[j],
                                                                        acc[i][j], 0, 0, 0);
        }
    }

    float bc[4];
#pragma unroll
    for (int j = 0; j < 4; j++) bc[j] = bias[col0 + wn + j * 16 + lr];
#pragma unroll
    for (int i = 0; i < 4; i++) {
#pragma unroll
        for (int r = 0; r < 4; r++) {
            int R = (int)row0 + wm + i * 16 + quad * 4 + r;
#pragma unroll
            for (int j = 0; j < 4; j++) {
                int Cc = (int)col0 + wn + j * 16 + lr;
                float val = acc[i][j][r] + bc[j];
                if (mode == 0) {
                    int t3 = Cc >> 10, rem = Cc & 1023;
                    int head = rem >> 6, d = rem & 63;
                    int lb = R >> 8, nn = R & 255;
                    if (t3 == 0) val *= 0.125f;  // Dh^-0.5
                    ((bf16*)outp)[(size_t)t3 * qstride +
                                  ((size_t)((lb << 4) + head) * NTOK + nn) * DH + d] = (bf16)val;
                } else if (mode == 2) {
                    ((bf16*)outp)[(size_t)R * N + Cc] = (bf16)gelu_f(val);
                } else {
                    val += resid[(size_t)R * N + Cc];
                    ((float*)outp)[(size_t)R * N + Cc] = val;
                }
            }
        }
    }
}

// ------------- MFMA flash attention: one workgroup per (b,h), wave = 64 queries ------
// LDS (64 KB total): K half (128 keys x 64d, chunk-swizzled), V^T half (packed 2k/word,
// chunk-swizzled), per-wave P/Q scratch (64q x 64, chunk-swizzled).
__global__ __launch_bounds__(256, 2) void attn_mfma(
    const bf16* __restrict__ qkv, const float* __restrict__ biasq,
    bf16* __restrict__ outp, size_t qstride) {
    __shared__ u32x4 Ks4[1024];      // 16 KB
    __shared__ unsigned Vt32[4096];  // 16 KB
    __shared__ u32x4 PQ4[2048];      // 32 KB

    int bh = blockIdx.x, lb = bh >> 4, h = bh & 15;
    int tid = threadIdx.x, wave = tid >> 6, lane = tid & 63;
    int quad = lane >> 4, lr = lane & 15;
    int wq = wave << 6;
    const unsigned short* qg = (const unsigned short*)qkv + (size_t)bh * 16384;

    // ---- stage this wave's Q tile into its PQ region (wave-private), read A-frags ----
    u32x4* pqw = PQ4 + wave * 512;
#pragma unroll
    for (int it = 0; it < 8; it++) {
        int c = it * 64 + lane;
        int qrow = c >> 3, p = c & 7;
        pqw[qrow * 8 + (p ^ (qrow & 7))] =
            *(const u32x4*)(qg + (size_t)(wq + qrow) * 64 + p * 8);
    }
    bf16x8 qf[4][2];
#pragma unroll
    for (int i = 0; i < 4; i++)
#pragma unroll
        for (int ks = 0; ks < 2; ks++) {
            int qrow = i * 16 + lr;
            qf[i][ks] = __builtin_bit_cast(bf16x8,
                pqw[qrow * 8 + (((ks << 2) + quad) ^ (qrow & 7))]);
        }

    f32x4 o[4][4] = {};
    float mrun[4][4], lpart[4][4];
#pragma unroll
    for (int i = 0; i < 4; i++)
#pragma unroll
        for (int r = 0; r < 4; r++) { mrun[i][r] = -1e30f; lpart[i][r] = 0.f; }

    const float* bq = biasq + (size_t)h * 65536;  // [q][k]

    for (int half = 0; half < 2; half++) {
        __syncthreads();
        // stage K half (128 keys x 64 d), chunk-swizzled rows
        const unsigned short* kg = (const unsigned short*)qkv + qstride +
                                   (size_t)bh * 16384 + half * 8192;
#pragma unroll
        for (int it = 0; it < 4; it++) {
            int c = it * 256 + tid;
            int kr = c >> 3, p = c & 7;
            Ks4[kr * 8 + (p ^ (kr & 7))] = *(const u32x4*)(kg + (size_t)kr * 64 + p * 8);
        }
        // stage V^T half: Vt[d][k] packed 2 keys/word, chunk-swizzled
        const unsigned short* vg = (const unsigned short*)qkv + 2 * qstride +
                                   (size_t)bh * 16384 + half * 8192;
#pragma unroll
        for (int it = 0; it < 16; it++) {
            int idx = it * 256 + tid;
            int d = idx & 63, k2 = idx >> 6;  // k2: key pair 0..63
            unsigned lo = vg[(size_t)(2 * k2) * 64 + d];
            unsigned hi = vg[(size_t)(2 * k2 + 1) * 64 + d];
            int ck = k2 >> 2, w = k2 & 3;
            Vt32[d * 64 + ((ck ^ (d & 15)) << 2) + w] = lo | (hi << 16);
        }
        __syncthreads();

        for (int kb = 0; kb < 2; kb++) {
            // ---- S = Q K^T (64q x 64k) ----
            f32x4 s[4][4] = {};
#pragma unroll
            for (int ks = 0; ks < 2; ks++) {
                bf16x8 kf[4];
#pragma unroll
                for (int j = 0; j < 4; j++) {
                    int kr = kb * 64 + j * 16 + lr;
                    kf[j] = __builtin_bit_cast(bf16x8,
                        Ks4[kr * 8 + (((ks << 2) + quad) ^ (kr & 7))]);
                }
#pragma unroll
                for (int i = 0; i < 4; i++)
#pragma unroll
                    for (int j = 0; j < 4; j++)
                        s[i][j] = __builtin_amdgcn_mfma_f32_16x16x32_bf16(
                            qf[i][ks], kf[j], s[i][j], 0, 0, 0);
            }
            // ---- bias + online softmax (C-layout: row q = quad*4+r, col k = j*16+lr) ----
            int kglob = half * 128 + kb * 64;
#pragma unroll
            for (int i = 0; i < 4; i++) {
#pragma unroll
                for (int r = 0; r < 4; r++) {
                    int q = wq + i * 16 + quad * 4 + r;
                    const float* brow = bq + (size_t)q * 256 + kglob + lr;
                    float v0 = s[i][0][r] + brow[0];
                    float v1 = s[i][1][r] + brow[16];
                    float v2 = s[i][2][r] + brow[32];
                    float v3 = s[i][3][r] + brow[48];
                    float mx = fmaxf(fmaxf(v0, v1), fmaxf(v2, v3));
                    mx = fmaxf(mx, __shfl_xor(mx, 1));
                    mx = fmaxf(mx, __shfl_xor(mx, 2));
                    mx = fmaxf(mx, __shfl_xor(mx, 4));
                    mx = fmaxf(mx, __shfl_xor(mx, 8));
                    float mnew = fmaxf(mrun[i][r], mx);
                    float alpha = __expf(mrun[i][r] - mnew);
                    mrun[i][r] = mnew;
                    v0 = __expf(v0 - mnew);
                    v1 = __expf(v1 - mnew);
                    v2 = __expf(v2 - mnew);
                    v3 = __expf(v3 - mnew);
                    lpart[i][r] = lpart[i][r] * alpha + (v0 + v1 + v2 + v3);
                    s[i][0][r] = v0; s[i][1][r] = v1; s[i][2][r] = v2; s[i][3][r] = v3;
#pragma unroll
                    for (int dj = 0; dj < 4; dj++) o[i][dj][r] *= alpha;
                }
            }
            // ---- P -> wave-private LDS scratch in A-layout-friendly rows ----
            bf16* pqb = (bf16*)pqw;
#pragma unroll
            for (int i = 0; i < 4; i++)
#pragma unroll
                for (int r = 0; r < 4; r++) {
                    int ql = i * 16 + quad * 4 + r;
#pragma unroll
                    for (int j = 0; j < 4; j++) {
                        int col = j * 16 + lr;
                        int ck = col >> 3;
                        pqb[ql * 64 + ((ck ^ (ql & 7)) << 3) + (col & 7)] =
                            (bf16)s[i][j][r];
                    }
                }
            __syncthreads();  // orders mixed-width LDS writes before b128 reads
            // ---- O += P V ----
#pragma unroll
            for (int ks2 = 0; ks2 < 2; ks2++) {
                bf16x8 pf[4], vf[4];
#pragma unroll
                for (int i = 0; i < 4; i++) {
                    int ql = i * 16 + lr;
                    pf[i] = __builtin_bit_cast(bf16x8,
                        pqw[ql * 8 + (((ks2 << 2) + quad) ^ (ql & 7))]);
                }
#pragma unroll
                for (int dj = 0; dj < 4; dj++) {
                    int d = dj * 16 + lr;
                    int ck = kb * 8 + ks2 * 4 + quad;
                    vf[dj] = __builtin_bit_cast(bf16x8,
                        *(const u32x4*)(Vt32 + d * 64 + ((ck ^ (d & 15)) << 2)));
                }
#pragma unroll
                for (int i = 0; i < 4; i++)
#pragma unroll
                    for (int dj = 0; dj < 4; dj++)
                        o[i][dj] = __builtin_amdgcn_mfma_f32_16x16x32_bf16(
                            pf[i], vf[dj], o[i][dj], 0, 0, 0);
            }
        }
    }

    // ---- finalize: 1/l scale, store merged-heads bf16 ----
#pragma unroll
    for (int i = 0; i < 4; i++)
#pragma unroll
        for (int r = 0; r < 4; r++) {
            float lp = lpart[i][r];
            lp += __shfl_xor(lp, 1);
            lp += __shfl_xor(lp, 2);
            lp += __shfl_xor(lp, 4);
            lp += __shfl_xor(lp, 8);
            float inv = 1.0f / lp;
            int row = lb * 256 + wq + i * 16 + quad * 4 + r;
            bf16* orow = outp + (size_t)row * CDIM + h * DH;
#pragma unroll
            for (int dj = 0; dj < 4; dj++)
                orow[dj * 16 + lr] = (bf16)(o[i][dj][r] * inv);
        }
}

// ---------------- launch ----------------
extern "C" void kernel_launch(void* const* d_in, const int* in_sizes, int n_in,
                              void* d_out, int out_size, void* d_ws, size_t ws_size,
                              hipStream_t stream) {
    const float* x      = (const float*)d_in[0];
    const int*   rpi    = (const int*)d_in[1];
    const float* qkv_w  = (const float*)d_in[2];
    const float* qkv_b  = (const float*)d_in[3];
    const float* proj_w = (const float*)d_in[4];
    const float* proj_b = (const float*)d_in[5];
    const float* rpb    = (const float*)d_in[6];
    const float* ln1g   = (const float*)d_in[7];
    const float* ln1b   = (const float*)d_in[8];
    const float* ln2g   = (const float*)d_in[9];
    const float* ln2b   = (const float*)d_in[10];
    const float* fc1_w  = (const float*)d_in[11];
    const float* fc1_b  = (const float*)d_in[12];
    const float* fc2_w  = (const float*)d_in[13];
    const float* fc2_b  = (const float*)d_in[14];
    float* out = (float*)d_out;
    char* ws = (char*)d_ws;

    // --- fixed region: bf16 transposed weights + fp32 biasq (29,360,128 B) ---
    bf16* qkvT   = (bf16*)(ws);                 // 6,291,456
    bf16* projT  = (bf16*)(ws + 6291456ull);    // 2,097,152
    bf16* fc1T   = (bf16*)(ws + 8388608ull);    // 8,388,608
    bf16* fc2T   = (bf16*)(ws + 16777216ull);   // 8,388,608
    float* biasq = (float*)(ws + 25165824ull);  // 4,194,304
    const size_t fixed_end = 29360128ull;

    // --- adaptive chunk: per-row bytes = 2048 (hbuf) + 8192 (qkv or ff) ---
    long long avail = (long long)ws_size - (long long)fixed_end;
    long long rc = avail / 10240;
    rc &= ~255LL;
    if (rc < 256) rc = 256;
    if (rc > MROWS) rc = MROWS;
    const int Rc = (int)rc;
    bf16* hbuf   = (bf16*)(ws + fixed_end);                        // Rc*1024 bf16
    bf16* bigbuf = (bf16*)(ws + fixed_end + (size_t)Rc * 2048ull); // Rc*3072 or Rc*4096 bf16

    transpose_f32_bf16<<<dim3(3072 / 32, 1024 / 32), 256, 0, stream>>>(qkv_w, qkvT, 1024, 3072);
    transpose_f32_bf16<<<dim3(1024 / 32, 1024 / 32), 256, 0, stream>>>(proj_w, projT, 1024, 1024);
    transpose_f32_bf16<<<dim3(4096 / 32, 1024 / 32), 256, 0, stream>>>(fc1_w, fc1T, 1024, 4096);
    transpose_f32_bf16<<<dim3(1024 / 32, 4096 / 32), 256, 0, stream>>>(fc2_w, fc2T, 4096, 1024);
    biasq_kernel<<<4096, 256, 0, stream>>>(rpi, rpb, biasq);

    // --- phase A: LN1 -> qkv -> attention -> proj + residual ---
    for (int r0 = 0; r0 < MROWS; r0 += Rc) {
        int m = MROWS - r0 < Rc ? MROWS - r0 : Rc;
        size_t qs = (size_t)m * 1024;  // per-q/k/v stride in bf16 elems
        ln_kernel<<<m, 256, 0, stream>>>(x + (size_t)r0 * CDIM, ln1g, ln1b, hbuf);
        gemm_bt_kernel<<<dim3(3072 / 128, m / 128), 256, 0, stream>>>(
            hbuf, qkvT, qkv_b, nullptr, bigbuf, qs, m, 3072, 1024, 0);
        attn_mfma<<<(m / 256) * NH, 256, 0, stream>>>(bigbuf, biasq, hbuf, qs);
        gemm_bt_kernel<<<dim3(1024 / 128, m / 128), 256, 0, stream>>>(
            hbuf, projT, proj_b, x + (size_t)r0 * CDIM, out + (size_t)r0 * CDIM, 0,
            m, 1024, 1024, 3);
    }

    // --- phase B: LN2 -> fc1+gelu -> fc2 + residual ---
    for (int r0 = 0; r0 < MROWS; r0 += Rc) {
        int m = MROWS - r0 < Rc ? MROWS - r0 : Rc;
        ln_kernel<<<m, 256, 0, stream>>>(out + (size_t)r0 * CDIM, ln2g, ln2b, hbuf);
        gemm_bt_kernel<<<dim3(4096 / 128, m / 128), 256, 0, stream>>>(
            hbuf, fc1T, fc1_b, nullptr, bigbuf, 0, m, 4096, 1024, 2);
        gemm_bt_kernel<<<dim3(1024 / 128, m / 128), 256, 0, stream>>>(
            bigbuf, fc2T, fc2_b, out + (size_t)r0 * CDIM, out + (size_t)r0 * CDIM, 0,
            m, 1024, 4096, 3);
    }
}